// Round 3
// baseline (589.853 us; speedup 1.0000x reference)
//
#include <hip/hip_runtime.h>
#include <hip/hip_bf16.h>

#define BT 1024
#define DD 1024
#define HH 2048
#define OO 1024
#define EE 8

typedef __bf16 bf16x8 __attribute__((ext_vector_type(8)));
typedef float  f32x4  __attribute__((ext_vector_type(4)));

// async global -> LDS, 16 bytes per lane. LDS dest must be wave-uniform base + lane*16.
__device__ __forceinline__ void cp16(void* l, const void* g) {
    __builtin_amdgcn_global_load_lds(
        (const __attribute__((address_space(1))) void*)g,
        (__attribute__((address_space(3))) void*)l, 16, 0, 0);
}

// ---------------- workspace layout (bytes) ----------------
// counts : int[8]            @ 0
// off    : int[9]            @ 256
// tok_e  : int[2048]         @ 1024
// tok_p  : int[2048]         @ 9216
// tok_w  : float[2048]       @ 17408
// elist  : int[8*1024]       @ 25600
// Xg     : bf16[3072*1024]   @ 65536       (end 6356992)
// H1     : bf16[3072*2048]   @ 6356992     (end 18939904)
// H2     : bf16[3072*2048]   @ 18939904    (end 31522816)
// Y      : f32 [3072*1024]   @ 31522816    (end 44105728)

// ---------------- router: logits -> softmax -> top2 -> renorm ----------------
__global__ __launch_bounds__(256) void router_kernel(
    const float* __restrict__ x, const float* __restrict__ Wr, const float* __restrict__ br,
    int* __restrict__ counts, int* __restrict__ elist,
    int* __restrict__ tok_e, int* __restrict__ tok_p, float* __restrict__ tok_w)
{
    int b = blockIdx.x;
    int tid = threadIdx.x;
    float acc[EE];
#pragma unroll
    for (int e = 0; e < EE; ++e) acc[e] = 0.f;
    const float* xr = x + (size_t)b * DD;
    for (int d = tid; d < DD; d += 256) {
        float xv = xr[d];
#pragma unroll
        for (int e = 0; e < EE; ++e) acc[e] += xv * Wr[d * EE + e];
    }
    __shared__ float red[4][EE];
    int lane = tid & 63, wv = tid >> 6;
#pragma unroll
    for (int e = 0; e < EE; ++e) {
        float v = acc[e];
#pragma unroll
        for (int o = 32; o > 0; o >>= 1) v += __shfl_down(v, o, 64);
        if (lane == 0) red[wv][e] = v;
    }
    __syncthreads();
    if (tid == 0) {
        float lg[EE];
#pragma unroll
        for (int e = 0; e < EE; ++e) lg[e] = red[0][e] + red[1][e] + red[2][e] + red[3][e] + br[e];
        float mx = lg[0];
#pragma unroll
        for (int e = 1; e < EE; ++e) mx = fmaxf(mx, lg[e]);
        float s = 0.f, p[EE];
#pragma unroll
        for (int e = 0; e < EE; ++e) { p[e] = expf(lg[e] - mx); s += p[e]; }
        float inv = 1.f / s;
#pragma unroll
        for (int e = 0; e < EE; ++e) p[e] *= inv;
        int i0 = 0; float b0 = p[0];
#pragma unroll
        for (int e = 1; e < EE; ++e) if (p[e] > b0) { b0 = p[e]; i0 = e; }
        int i1 = -1; float b1v = -1.f;
#pragma unroll
        for (int e = 0; e < EE; ++e) if (e != i0 && p[e] > b1v) { b1v = p[e]; i1 = e; }
        float s2 = b0 + b1v + 1e-6f;
        float w0 = b0 / s2, w1 = b1v / s2;
        int p0 = atomicAdd(&counts[i0], 1);
        int p1 = atomicAdd(&counts[i1], 1);
        elist[i0 * 1024 + p0] = b;
        elist[i1 * 1024 + p1] = b;
        tok_e[2 * b] = i0; tok_e[2 * b + 1] = i1;
        tok_p[2 * b] = p0; tok_p[2 * b + 1] = p1;
        tok_w[2 * b] = w0; tok_w[2 * b + 1] = w1;
    }
}

// ---------------- padded prefix sum of counts ----------------
__global__ void offsets_kernel(const int* __restrict__ counts, int* __restrict__ off)
{
    if (threadIdx.x == 0 && blockIdx.x == 0) {
        int a = 0;
        for (int e = 0; e < EE; ++e) {
            off[e] = a;
            a += ((counts[e] + 127) >> 7) << 7;   // pad each expert region to 128 rows
        }
        off[EE] = a;
    }
}

// ---------------- gather x rows -> bf16, pad rows zeroed ----------------
__global__ __launch_bounds__(256) void gather_kernel(
    const float* __restrict__ x, const int* __restrict__ counts, const int* __restrict__ off,
    const int* __restrict__ elist, __bf16* __restrict__ Xg)
{
    int e = blockIdx.y;
    int chunk = blockIdx.x >> 2;      // 128-row chunk
    int rg = blockIdx.x & 3;          // 32-row group within chunk
    int cnt = counts[e];
    if (chunk * 128 >= cnt) return;
    int base = off[e] + chunk * 128 + rg * 32;
    int tid = threadIdx.x;
    for (int it = 0; it < 32; ++it) {
        int slot = chunk * 128 + rg * 32 + it;
        __bf16 v[4];
        if (slot < cnt) {
            int tok = elist[e * 1024 + slot];
            const float4 f = *(const float4*)(x + (size_t)tok * DD + tid * 4);
            v[0] = (__bf16)f.x; v[1] = (__bf16)f.y; v[2] = (__bf16)f.z; v[3] = (__bf16)f.w;
        } else {
            v[0] = v[1] = v[2] = v[3] = (__bf16)0.f;
        }
        *(uint2*)(Xg + (size_t)(base + it) * DD + tid * 4) = *(uint2*)v;
    }
}

// ---------------- fused MFMA GEMM: C[rows,N] = A[rows,K](bf16) * W[e][K,N](fp32) + bias ----
// A staged via global_load_lds (bf16). W converted fp32->bf16 in-register each k-step.
// TM=128 rows; TN columns per block (64 or 32) -> 32nt x ~2mt x 8e = ~512 active blocks.
template <int K, int N, int TN, int RELU_BF16>
__global__ __launch_bounds__(256) void gemm_fused(
    const __bf16* __restrict__ A, const float* __restrict__ Wall,
    const float* __restrict__ bias, void* __restrict__ Cout,
    const int* __restrict__ counts, const int* __restrict__ off)
{
    constexpr int JW = TN / 32;       // 16-wide j-frags per wave (wave covers TN/2 cols)
    constexpr int KC = TN / 8;        // k-elements of W per thread per step (8 or 4)
    int e = blockIdx.z, mt = blockIdx.y, nt = blockIdx.x;
    int cnt = counts[e];
    if (mt * 128 >= cnt) return;
    int row0 = off[e] + mt * 128;
    const __bf16* Ab = A + (size_t)row0 * K;
    const float*  Wp = Wall + (size_t)e * K * N + nt * TN;

    __shared__ __bf16 As[128 * 32];   // [m][k] contiguous (DMA lane order)
    __shared__ __bf16 Bs[TN * 32];    // [n][k] contiguous

    int tid = threadIdx.x;
    int wave = tid >> 6, lane = tid & 63;
    int m = lane & 15, q = lane >> 4;
    int wm = (wave >> 1) * 64, wn = (wave & 1) * (TN / 2);

    // A DMA mapping: LDS addr = wave-uniform + lane*16  <=>  row (s*64+wave*16+lane/4), k8=(lane&3)*8
    int ar = (tid >> 6) * 16 + ((tid & 63) >> 2);
    int k8 = (tid & 3) * 8;

    // B stage mapping: thread owns column n, KC consecutive k's
    int bn = tid % TN;
    int bkc = (tid / TN) * KC;

    f32x4 acc[4][JW] = {};

    for (int k0 = 0; k0 < K; k0 += 32) {
#pragma unroll
        for (int s = 0; s < 2; ++s)
            cp16(&As[(s * 64 + ar) * 32 + k8], Ab + (size_t)(s * 64 + ar) * K + k0 + k8);
        {
            __bf16 tmp[KC];
#pragma unroll
            for (int g = 0; g < KC; ++g)
                tmp[g] = (__bf16)Wp[(size_t)(k0 + bkc + g) * N + bn];
            if (KC == 8)
                *(uint4*)(&Bs[bn * 32 + bkc]) = *(uint4*)tmp;
            else
                *(uint2*)(&Bs[bn * 32 + bkc]) = *(uint2*)tmp;
        }
        __syncthreads();

        bf16x8 af[4], bfr[JW];
#pragma unroll
        for (int i = 0; i < 4; ++i)
            af[i] = *(bf16x8*)(&As[(wm + i * 16 + m) * 32 + q * 8]);
#pragma unroll
        for (int j = 0; j < JW; ++j)
            bfr[j] = *(bf16x8*)(&Bs[(wn + j * 16 + m) * 32 + q * 8]);
#pragma unroll
        for (int i = 0; i < 4; ++i)
#pragma unroll
            for (int j = 0; j < JW; ++j)
                acc[i][j] = __builtin_amdgcn_mfma_f32_16x16x32_bf16(af[i], bfr[j], acc[i][j], 0, 0, 0);
        __syncthreads();
    }

    int colbase = nt * TN + wn;
#pragma unroll
    for (int j = 0; j < JW; ++j) {
        int col = colbase + j * 16 + m;
        float bv = bias[(size_t)e * N + col];
#pragma unroll
        for (int i = 0; i < 4; ++i) {
            int rbase = row0 + wm + i * 16 + q * 4;
#pragma unroll
            for (int r = 0; r < 4; ++r) {
                float v = acc[i][j][r] + bv;
                if (RELU_BF16) {
                    v = fmaxf(v, 0.f);
                    ((__bf16*)Cout)[(size_t)(rbase + r) * N + col] = (__bf16)v;
                } else {
                    ((float*)Cout)[(size_t)(rbase + r) * N + col] = v;
                }
            }
        }
    }
}

// ---------------- combine: out[b] = w0*Y[r0] + w1*Y[r1] ----------------
__global__ __launch_bounds__(256) void combine_kernel(
    const float* __restrict__ Y, const int* __restrict__ off,
    const int* __restrict__ tok_e, const int* __restrict__ tok_p,
    const float* __restrict__ tok_w, float* __restrict__ out)
{
    int b = blockIdx.x, t = threadIdx.x;
    int e0 = tok_e[2 * b], e1 = tok_e[2 * b + 1];
    int r0 = off[e0] + tok_p[2 * b];
    int r1 = off[e1] + tok_p[2 * b + 1];
    float w0 = tok_w[2 * b], w1 = tok_w[2 * b + 1];
    float4 a = *(const float4*)(Y + (size_t)r0 * OO + t * 4);
    float4 c = *(const float4*)(Y + (size_t)r1 * OO + t * 4);
    float4 o;
    o.x = w0 * a.x + w1 * c.x;
    o.y = w0 * a.y + w1 * c.y;
    o.z = w0 * a.z + w1 * c.z;
    o.w = w0 * a.w + w1 * c.w;
    *(float4*)(out + (size_t)b * OO + t * 4) = o;
}

extern "C" void kernel_launch(void* const* d_in, const int* in_sizes, int n_in,
                              void* d_out, int out_size, void* d_ws, size_t ws_size,
                              hipStream_t stream)
{
    (void)in_sizes; (void)n_in; (void)out_size; (void)ws_size;
    const float* x  = (const float*)d_in[0];
    const float* Wr = (const float*)d_in[1];
    const float* br = (const float*)d_in[2];
    const float* W1 = (const float*)d_in[3];
    const float* b1 = (const float*)d_in[4];
    const float* W2 = (const float*)d_in[5];
    const float* b2 = (const float*)d_in[6];
    const float* W3 = (const float*)d_in[7];
    const float* b3 = (const float*)d_in[8];
    float* out = (float*)d_out;

    char* ws = (char*)d_ws;
    int*    counts = (int*)(ws + 0);
    int*    off    = (int*)(ws + 256);
    int*    tok_e  = (int*)(ws + 1024);
    int*    tok_p  = (int*)(ws + 9216);
    float*  tok_w  = (float*)(ws + 17408);
    int*    elist  = (int*)(ws + 25600);
    __bf16* Xg     = (__bf16*)(ws + 65536);
    __bf16* H1     = (__bf16*)(ws + 6356992);
    __bf16* H2     = (__bf16*)(ws + 18939904);
    float*  Y      = (float*)(ws + 31522816);

    hipMemsetAsync(counts, 0, 256, stream);
    router_kernel<<<1024, 256, 0, stream>>>(x, Wr, br, counts, elist, tok_e, tok_p, tok_w);
    offsets_kernel<<<1, 64, 0, stream>>>(counts, off);
    gather_kernel<<<dim3(32, 8), 256, 0, stream>>>(x, counts, off, elist, Xg);

    // TM=128 everywhere; TN sized so every GEMM has ~512 active blocks (2 blocks/CU).
    gemm_fused<1024, 2048, 64, 1><<<dim3(32, 8, 8), 256, 0, stream>>>(Xg, W1, b1, (void*)H1, counts, off);
    gemm_fused<2048, 2048, 64, 1><<<dim3(32, 8, 8), 256, 0, stream>>>(H1, W2, b2, (void*)H2, counts, off);
    gemm_fused<2048, 1024, 32, 0><<<dim3(32, 8, 8), 256, 0, stream>>>(H2, W3, b3, (void*)Y, counts, off);

    combine_kernel<<<1024, 256, 0, stream>>>(Y, off, tok_e, tok_p, tok_w, out);
}

// Round 4
// 531.866 us; speedup vs baseline: 1.1090x; 1.1090x over previous
//
#include <hip/hip_runtime.h>
#include <hip/hip_bf16.h>

#define BT 1024
#define DD 1024
#define HH 2048
#define OO 1024
#define EE 8

typedef __bf16 bf16x8 __attribute__((ext_vector_type(8)));
typedef float  f32x4  __attribute__((ext_vector_type(4)));

// ---------------- workspace layout (bytes) ----------------
// counts : int[8]            @ 0
// off    : int[9]            @ 256
// tok_e  : int[2048]         @ 1024
// tok_p  : int[2048]         @ 9216
// tok_w  : float[2048]       @ 17408
// elist  : int[8*1024]       @ 25600
// Xg     : bf16[3072*1024]   @ 65536       (end 6356992)
// H1     : bf16[3072*2048]   @ 6356992     (end 18939904)
// H2     : bf16[3072*2048]   @ 18939904    (end 31522816)
// Y      : f32 [3072*1024]   @ 31522816    (end 44105728)

// ---------------- router ----------------
__global__ __launch_bounds__(256) void router_kernel(
    const float* __restrict__ x, const float* __restrict__ Wr, const float* __restrict__ br,
    int* __restrict__ counts, int* __restrict__ elist,
    int* __restrict__ tok_e, int* __restrict__ tok_p, float* __restrict__ tok_w)
{
    int b = blockIdx.x;
    int tid = threadIdx.x;
    float acc[EE];
#pragma unroll
    for (int e = 0; e < EE; ++e) acc[e] = 0.f;
    const float* xr = x + (size_t)b * DD;
    for (int d = tid; d < DD; d += 256) {
        float xv = xr[d];
#pragma unroll
        for (int e = 0; e < EE; ++e) acc[e] += xv * Wr[d * EE + e];
    }
    __shared__ float red[4][EE];
    int lane = tid & 63, wv = tid >> 6;
#pragma unroll
    for (int e = 0; e < EE; ++e) {
        float v = acc[e];
#pragma unroll
        for (int o = 32; o > 0; o >>= 1) v += __shfl_down(v, o, 64);
        if (lane == 0) red[wv][e] = v;
    }
    __syncthreads();
    if (tid == 0) {
        float lg[EE];
#pragma unroll
        for (int e = 0; e < EE; ++e) lg[e] = red[0][e] + red[1][e] + red[2][e] + red[3][e] + br[e];
        float mx = lg[0];
#pragma unroll
        for (int e = 1; e < EE; ++e) mx = fmaxf(mx, lg[e]);
        float s = 0.f, p[EE];
#pragma unroll
        for (int e = 0; e < EE; ++e) { p[e] = expf(lg[e] - mx); s += p[e]; }
        float inv = 1.f / s;
#pragma unroll
        for (int e = 0; e < EE; ++e) p[e] *= inv;
        int i0 = 0; float b0 = p[0];
#pragma unroll
        for (int e = 1; e < EE; ++e) if (p[e] > b0) { b0 = p[e]; i0 = e; }
        int i1 = -1; float b1v = -1.f;
#pragma unroll
        for (int e = 0; e < EE; ++e) if (e != i0 && p[e] > b1v) { b1v = p[e]; i1 = e; }
        float s2 = b0 + b1v + 1e-6f;
        float w0 = b0 / s2, w1 = b1v / s2;
        int p0 = atomicAdd(&counts[i0], 1);
        int p1 = atomicAdd(&counts[i1], 1);
        elist[i0 * 1024 + p0] = b;
        elist[i1 * 1024 + p1] = b;
        tok_e[2 * b] = i0; tok_e[2 * b + 1] = i1;
        tok_p[2 * b] = p0; tok_p[2 * b + 1] = p1;
        tok_w[2 * b] = w0; tok_w[2 * b + 1] = w1;
    }
}

// ---------------- padded prefix sum ----------------
__global__ void offsets_kernel(const int* __restrict__ counts, int* __restrict__ off)
{
    if (threadIdx.x == 0 && blockIdx.x == 0) {
        int a = 0;
        for (int e = 0; e < EE; ++e) {
            off[e] = a;
            a += ((counts[e] + 127) >> 7) << 7;
        }
        off[EE] = a;
    }
}

// ---------------- gather x rows -> bf16, pad rows zeroed ----------------
__global__ __launch_bounds__(256) void gather_kernel(
    const float* __restrict__ x, const int* __restrict__ counts, const int* __restrict__ off,
    const int* __restrict__ elist, __bf16* __restrict__ Xg)
{
    int e = blockIdx.y;
    int chunk = blockIdx.x >> 2;
    int rg = blockIdx.x & 3;
    int cnt = counts[e];
    if (chunk * 128 >= cnt) return;
    int base = off[e] + chunk * 128 + rg * 32;
    int tid = threadIdx.x;
    for (int it = 0; it < 32; ++it) {
        int slot = chunk * 128 + rg * 32 + it;
        __bf16 v[4];
        if (slot < cnt) {
            int tok = elist[e * 1024 + slot];
            const float4 f = *(const float4*)(x + (size_t)tok * DD + tid * 4);
            v[0] = (__bf16)f.x; v[1] = (__bf16)f.y; v[2] = (__bf16)f.z; v[3] = (__bf16)f.w;
        } else {
            v[0] = v[1] = v[2] = v[3] = (__bf16)0.f;
        }
        *(uint2*)(Xg + (size_t)(base + it) * DD + tid * 4) = *(uint2*)v;
    }
}

// ---------------- pipelined MFMA GEMM ----------------
// C[rows,N] = A[rows,K](bf16) * W[e][K,N](fp32->bf16 in-reg) + bias
// BK=64. W prefetched depth-2 in regs; A frags direct-from-global, depth-1.
// Raw s_barrier + lgkmcnt(0) only: in-flight global loads survive the barrier.
template <int K, int N, int TM, int RELU_BF16>
__global__ __launch_bounds__(256, 3) void gemm_pipe(
    const __bf16* __restrict__ A, const float* __restrict__ Wall,
    const float* __restrict__ bias, void* __restrict__ Cout,
    const int* __restrict__ counts, const int* __restrict__ off)
{
    constexpr int TN = 64;
    constexpr int IW = TM / 32;       // i-frags per wave (rows/wave = TM/2)
    constexpr int JW = 2;             // j-frags per wave (cols/wave = 32)
    constexpr int S = K / 64;         // k-steps

    int e = blockIdx.z, mt = blockIdx.y, nt = blockIdx.x;
    int cnt = counts[e];
    if (mt * TM >= cnt) return;
    int row0 = off[e] + mt * TM;
    const __bf16* Ab = A + (size_t)row0 * K;
    const float*  Wp = Wall + (size_t)e * K * N + nt * TN;

    __shared__ __bf16 Bs[2][64 * 72];   // [buf][n*72 + k]; 144B rows (16B-aligned, bank-spread)

    int tid = threadIdx.x;
    int wave = tid >> 6, lane = tid & 63;
    int m = lane & 15, q = lane >> 4;
    int wm = (wave >> 1) * (TM / 2), wn = (wave & 1) * 32;

    int bn = tid & 63;                // W-stage: column
    int bkc = (tid >> 6) * 16;        // W-stage: k-chunk base (16 rows per thread)

    f32x4 acc[IW][JW] = {};
    uint4 afA[IW][2], afB[IW][2];
    float wA[16], wB[16];

    auto loadW = [&](float (&dst)[16], int s) {
        int ks = s * 64; if (ks >= K) ks = 0;      // clamp: harmless, never consumed meaningfully
        const float* p = Wp + (size_t)(ks + bkc) * N + bn;
#pragma unroll
        for (int g = 0; g < 16; ++g) dst[g] = p[(size_t)g * N];
    };
    auto loadA = [&](uint4 (&dst)[IW][2], int s) {
        int ks = s * 64; if (ks >= K) ks = 0;
#pragma unroll
        for (int i = 0; i < IW; ++i)
#pragma unroll
            for (int h = 0; h < 2; ++h)
                dst[i][h] = *(const uint4*)(Ab + (size_t)(wm + i * 16 + m) * K + ks + h * 32 + q * 8);
    };
    auto stageB = [&](const float (&w)[16], int buf) {
        __bf16 t16[16];
#pragma unroll
        for (int g = 0; g < 16; ++g) t16[g] = (__bf16)w[g];
        *(uint4*)(&Bs[buf][bn * 72 + bkc]) = *(uint4*)&t16[0];
        *(uint4*)(&Bs[buf][bn * 72 + bkc + 8]) = *(uint4*)&t16[8];
    };
    auto compute = [&](uint4 (&af)[IW][2], int buf) {
        bf16x8 bfr[JW][2];
#pragma unroll
        for (int j = 0; j < JW; ++j)
#pragma unroll
            for (int h = 0; h < 2; ++h)
                bfr[j][h] = *(bf16x8*)(&Bs[buf][(wn + j * 16 + m) * 72 + h * 32 + q * 8]);
#pragma unroll
        for (int i = 0; i < IW; ++i)
#pragma unroll
            for (int j = 0; j < JW; ++j)
#pragma unroll
                for (int h = 0; h < 2; ++h)
                    acc[i][j] = __builtin_amdgcn_mfma_f32_16x16x32_bf16(
                        *(bf16x8*)&af[i][h], bfr[j][h], acc[i][j], 0, 0, 0);
    };

    // prologue
    loadA(afA, 0);
    loadW(wA, 0);
    loadW(wB, 1);
    stageB(wA, 0);                       // waits only wA (wB stays in flight)
    __builtin_amdgcn_s_waitcnt(0xC07F);  // lgkmcnt(0) only
    __builtin_amdgcn_s_barrier();

    for (int p = 0; p < S / 2; ++p) {
        int t = 2 * p;
        // even step: compute buf0, stage buf1 from wB, prefetch W(t+2)->wA, A(t+1)->afB
        loadA(afB, t + 1);
        loadW(wA, t + 2);
        compute(afA, 0);
        stageB(wB, 1);
        __builtin_amdgcn_s_waitcnt(0xC07F);
        __builtin_amdgcn_s_barrier();
        // odd step: compute buf1, stage buf0 from wA, prefetch W(t+3)->wB, A(t+2)->afA
        loadA(afA, t + 2);
        loadW(wB, t + 3);
        compute(afB, 1);
        stageB(wA, 0);
        __builtin_amdgcn_s_waitcnt(0xC07F);
        __builtin_amdgcn_s_barrier();
    }

    // epilogue: D[row = q*4 + r][col = m] per 16x16 subtile
    int colbase = nt * TN + wn;
#pragma unroll
    for (int j = 0; j < JW; ++j) {
        int col = colbase + j * 16 + m;
        float bv = bias[(size_t)e * N + col];
#pragma unroll
        for (int i = 0; i < IW; ++i) {
            int rbase = row0 + wm + i * 16 + q * 4;
#pragma unroll
            for (int r = 0; r < 4; ++r) {
                float v = acc[i][j][r] + bv;
                if (RELU_BF16) {
                    v = fmaxf(v, 0.f);
                    ((__bf16*)Cout)[(size_t)(rbase + r) * N + col] = (__bf16)v;
                } else {
                    ((float*)Cout)[(size_t)(rbase + r) * N + col] = v;
                }
            }
        }
    }
}

// ---------------- combine: out[b] = w0*Y[r0] + w1*Y[r1] ----------------
__global__ __launch_bounds__(256) void combine_kernel(
    const float* __restrict__ Y, const int* __restrict__ off,
    const int* __restrict__ tok_e, const int* __restrict__ tok_p,
    const float* __restrict__ tok_w, float* __restrict__ out)
{
    int b = blockIdx.x, t = threadIdx.x;
    int e0 = tok_e[2 * b], e1 = tok_e[2 * b + 1];
    int r0 = off[e0] + tok_p[2 * b];
    int r1 = off[e1] + tok_p[2 * b + 1];
    float w0 = tok_w[2 * b], w1 = tok_w[2 * b + 1];
    float4 a = *(const float4*)(Y + (size_t)r0 * OO + t * 4);
    float4 c = *(const float4*)(Y + (size_t)r1 * OO + t * 4);
    float4 o;
    o.x = w0 * a.x + w1 * c.x;
    o.y = w0 * a.y + w1 * c.y;
    o.z = w0 * a.z + w1 * c.z;
    o.w = w0 * a.w + w1 * c.w;
    *(float4*)(out + (size_t)b * OO + t * 4) = o;
}

extern "C" void kernel_launch(void* const* d_in, const int* in_sizes, int n_in,
                              void* d_out, int out_size, void* d_ws, size_t ws_size,
                              hipStream_t stream)
{
    (void)in_sizes; (void)n_in; (void)out_size; (void)ws_size;
    const float* x  = (const float*)d_in[0];
    const float* Wr = (const float*)d_in[1];
    const float* br = (const float*)d_in[2];
    const float* W1 = (const float*)d_in[3];
    const float* b1 = (const float*)d_in[4];
    const float* W2 = (const float*)d_in[5];
    const float* b2 = (const float*)d_in[6];
    const float* W3 = (const float*)d_in[7];
    const float* b3 = (const float*)d_in[8];
    float* out = (float*)d_out;

    char* ws = (char*)d_ws;
    int*    counts = (int*)(ws + 0);
    int*    off    = (int*)(ws + 256);
    int*    tok_e  = (int*)(ws + 1024);
    int*    tok_p  = (int*)(ws + 9216);
    float*  tok_w  = (float*)(ws + 17408);
    int*    elist  = (int*)(ws + 25600);
    __bf16* Xg     = (__bf16*)(ws + 65536);
    __bf16* H1     = (__bf16*)(ws + 6356992);
    __bf16* H2     = (__bf16*)(ws + 18939904);
    float*  Y      = (float*)(ws + 31522816);

    hipMemsetAsync(counts, 0, 256, stream);
    router_kernel<<<1024, 256, 0, stream>>>(x, Wr, br, counts, elist, tok_e, tok_p, tok_w);
    offsets_kernel<<<1, 64, 0, stream>>>(counts, off);
    gather_kernel<<<dim3(32, 8), 256, 0, stream>>>(x, counts, off, elist, Xg);

    // TM=128 for gemm1/2 (nt=32 -> ~512 active blocks), TM=64 for gemm3 (nt=16 -> ~512).
    gemm_pipe<1024, 2048, 128, 1><<<dim3(32, 8, 8), 256, 0, stream>>>(Xg, W1, b1, (void*)H1, counts, off);
    gemm_pipe<2048, 2048, 128, 1><<<dim3(32, 8, 8), 256, 0, stream>>>(H1, W2, b2, (void*)H2, counts, off);
    gemm_pipe<2048, 1024, 64, 0><<<dim3(16, 16, 8), 256, 0, stream>>>(H2, W3, b3, (void*)Y, counts, off);

    combine_kernel<<<1024, 256, 0, stream>>>(Y, off, tok_e, tok_p, tok_w, out);
}

// Round 5
// 468.862 us; speedup vs baseline: 1.2581x; 1.1344x over previous
//
#include <hip/hip_runtime.h>
#include <hip/hip_bf16.h>

#define BT 1024
#define DD 1024
#define HH 2048
#define OO 1024
#define EE 8
#define RMAX 3072   // max padded rows (1024 tokens * 2 assignments, padded per expert)

typedef __bf16 bf16x8 __attribute__((ext_vector_type(8)));
typedef float  f32x4  __attribute__((ext_vector_type(4)));

// async global -> LDS, 16 bytes per lane. LDS dest must be wave-uniform base + lane*16.
__device__ __forceinline__ void cp16(void* l, const void* g) {
    __builtin_amdgcn_global_load_lds(
        (const __attribute__((address_space(1))) void*)g,
        (__attribute__((address_space(3))) void*)l, 16, 0, 0);
}

// ---------------- workspace layout (bytes) ----------------
// counts : int[8]              @ 0
// off    : int[9]              @ 256
// tok_e  : int[2048]           @ 1024
// tok_p  : int[2048]           @ 9216
// tok_w  : float[2048]         @ 17408
// elist  : int[8*1024]         @ 25600
// Xg     : bf16[3072*1024]     @ 65536       (end 6356992)
// H1     : bf16[3072*2048]     @ 6356992     (end 18939904)
// H2     : bf16[3072*2048]     @ 18939904    (end 31522816)
// P1     : f32[2][3072*2048]   @ 31522816    (end 81854464)
// P2     : f32[2][3072*2048]   @ 81854464    (end 132186112)
// P3     : f32[4][3072*1024]   @ 132186112   (end 182517760)

// ---------------- router: logits -> softmax -> top2 -> renorm ----------------
__global__ __launch_bounds__(256) void router_kernel(
    const float* __restrict__ x, const float* __restrict__ Wr, const float* __restrict__ br,
    int* __restrict__ counts, int* __restrict__ elist,
    int* __restrict__ tok_e, int* __restrict__ tok_p, float* __restrict__ tok_w)
{
    int b = blockIdx.x;
    int tid = threadIdx.x;
    float acc[EE];
#pragma unroll
    for (int e = 0; e < EE; ++e) acc[e] = 0.f;
    const float* xr = x + (size_t)b * DD;
    for (int d = tid; d < DD; d += 256) {
        float xv = xr[d];
#pragma unroll
        for (int e = 0; e < EE; ++e) acc[e] += xv * Wr[d * EE + e];
    }
    __shared__ float red[4][EE];
    int lane = tid & 63, wv = tid >> 6;
#pragma unroll
    for (int e = 0; e < EE; ++e) {
        float v = acc[e];
#pragma unroll
        for (int o = 32; o > 0; o >>= 1) v += __shfl_down(v, o, 64);
        if (lane == 0) red[wv][e] = v;
    }
    __syncthreads();
    if (tid == 0) {
        float lg[EE];
#pragma unroll
        for (int e = 0; e < EE; ++e) lg[e] = red[0][e] + red[1][e] + red[2][e] + red[3][e] + br[e];
        float mx = lg[0];
#pragma unroll
        for (int e = 1; e < EE; ++e) mx = fmaxf(mx, lg[e]);
        float s = 0.f, p[EE];
#pragma unroll
        for (int e = 0; e < EE; ++e) { p[e] = expf(lg[e] - mx); s += p[e]; }
        float inv = 1.f / s;
#pragma unroll
        for (int e = 0; e < EE; ++e) p[e] *= inv;
        int i0 = 0; float b0 = p[0];
#pragma unroll
        for (int e = 1; e < EE; ++e) if (p[e] > b0) { b0 = p[e]; i0 = e; }
        int i1 = -1; float b1v = -1.f;
#pragma unroll
        for (int e = 0; e < EE; ++e) if (e != i0 && p[e] > b1v) { b1v = p[e]; i1 = e; }
        float s2 = b0 + b1v + 1e-6f;
        float w0 = b0 / s2, w1 = b1v / s2;
        int p0 = atomicAdd(&counts[i0], 1);
        int p1 = atomicAdd(&counts[i1], 1);
        elist[i0 * 1024 + p0] = b;
        elist[i1 * 1024 + p1] = b;
        tok_e[2 * b] = i0; tok_e[2 * b + 1] = i1;
        tok_p[2 * b] = p0; tok_p[2 * b + 1] = p1;
        tok_w[2 * b] = w0; tok_w[2 * b + 1] = w1;
    }
}

// ---------------- padded prefix sum ----------------
__global__ void offsets_kernel(const int* __restrict__ counts, int* __restrict__ off)
{
    if (threadIdx.x == 0 && blockIdx.x == 0) {
        int a = 0;
        for (int e = 0; e < EE; ++e) {
            off[e] = a;
            a += ((counts[e] + 127) >> 7) << 7;
        }
        off[EE] = a;
    }
}

// ---------------- gather x rows -> bf16, pad rows zeroed ----------------
__global__ __launch_bounds__(256) void gather_kernel(
    const float* __restrict__ x, const int* __restrict__ counts, const int* __restrict__ off,
    const int* __restrict__ elist, __bf16* __restrict__ Xg)
{
    int e = blockIdx.y;
    int chunk = blockIdx.x >> 2;
    int rg = blockIdx.x & 3;
    int cnt = counts[e];
    if (chunk * 128 >= cnt) return;
    int base = off[e] + chunk * 128 + rg * 32;
    int tid = threadIdx.x;
    for (int it = 0; it < 32; ++it) {
        int slot = chunk * 128 + rg * 32 + it;
        __bf16 v[4];
        if (slot < cnt) {
            int tok = elist[e * 1024 + slot];
            const float4 f = *(const float4*)(x + (size_t)tok * DD + tid * 4);
            v[0] = (__bf16)f.x; v[1] = (__bf16)f.y; v[2] = (__bf16)f.z; v[3] = (__bf16)f.w;
        } else {
            v[0] = v[1] = v[2] = v[3] = (__bf16)0.f;
        }
        *(uint2*)(Xg + (size_t)(base + it) * DD + tid * 4) = *(uint2*)v;
    }
}

// ---------------- split-K MFMA GEMM ----------------
// P[kp][rows,N] = A[rows, kp-chunk of K](bf16) * W[e][kp-chunk, N](fp32->bf16 in-reg)
// TM=128, TN=64, BK=32. No bias here (added once in the reduce pass).
// Grid: (N/TN, 8*KSPLIT, EE); y = mt*KSPLIT + kp. ~1024 active blocks => ~4/CU.
template <int K, int N, int KSPLIT>
__global__ __launch_bounds__(256) void gemm_splitk(
    const __bf16* __restrict__ A, const float* __restrict__ Wall,
    float* __restrict__ P, const int* __restrict__ counts, const int* __restrict__ off)
{
    constexpr int TN = 64;
    constexpr int KC = K / KSPLIT;
    int e = blockIdx.z;
    int mt = blockIdx.y / KSPLIT;
    int kp = blockIdx.y % KSPLIT;
    int nt = blockIdx.x;
    int cnt = counts[e];
    if (mt * 128 >= cnt) return;
    int row0 = off[e] + mt * 128;

    const __bf16* Ab = A + (size_t)row0 * K + (size_t)kp * KC;
    const float*  Wp = Wall + (size_t)e * K * N + (size_t)kp * KC * N + nt * TN;
    float* Pp = P + (size_t)kp * RMAX * N;

    __shared__ __bf16 As[128 * 32];   // [m][k] contiguous (DMA lane order)
    __shared__ __bf16 Bs[64 * 40];    // [n][k] stride 40 (80B rows: bank-spread, 16B-aligned)

    int tid = threadIdx.x;
    int wave = tid >> 6, lane = tid & 63;
    int m = lane & 15, q = lane >> 4;
    int wm = (wave >> 1) * 64, wn = (wave & 1) * 32;

    // A-DMA mapping: LDS byte addr = wave-uniform + lane*16
    int ar = (tid >> 6) * 16 + ((tid & 63) >> 2);
    int k8 = (tid & 3) * 8;
    // W-stage mapping: thread owns column bn, 8 consecutive k's
    int bn = tid & 63;
    int bkc = (tid >> 6) * 8;

    f32x4 acc[4][2] = {};

    for (int k0 = 0; k0 < KC; k0 += 32) {
        cp16(&As[ar * 32 + k8],        Ab + (size_t)ar * K + k0 + k8);
        cp16(&As[(64 + ar) * 32 + k8], Ab + (size_t)(64 + ar) * K + k0 + k8);
        {
            __bf16 t8[8];
            const float* p = Wp + (size_t)(k0 + bkc) * N + bn;
#pragma unroll
            for (int g = 0; g < 8; ++g) t8[g] = (__bf16)p[(size_t)g * N];
            *(uint4*)(&Bs[bn * 40 + bkc]) = *(uint4*)t8;
        }
        __syncthreads();

        bf16x8 af[4], bfr[2];
#pragma unroll
        for (int i = 0; i < 4; ++i)
            af[i] = *(bf16x8*)(&As[(wm + i * 16 + m) * 32 + q * 8]);
#pragma unroll
        for (int j = 0; j < 2; ++j)
            bfr[j] = *(bf16x8*)(&Bs[(wn + j * 16 + m) * 40 + q * 8]);
#pragma unroll
        for (int i = 0; i < 4; ++i)
#pragma unroll
            for (int j = 0; j < 2; ++j)
                acc[i][j] = __builtin_amdgcn_mfma_f32_16x16x32_bf16(af[i], bfr[j], acc[i][j], 0, 0, 0);
        __syncthreads();
    }

    // partial store (fp32, no bias). D[row = q*4+r][col = m] per 16x16 subtile.
    int colbase = nt * TN + wn;
#pragma unroll
    for (int j = 0; j < 2; ++j) {
        int col = colbase + j * 16 + m;
#pragma unroll
        for (int i = 0; i < 4; ++i) {
            int rbase = row0 + wm + i * 16 + q * 4;
#pragma unroll
            for (int r = 0; r < 4; ++r)
                Pp[(size_t)(rbase + r) * N + col] = acc[i][j][r];
        }
    }
}

// ---------------- reduce partials + bias + relu -> bf16 ----------------
// grid: (N/1024, RMAX). Row -> expert via off[] scan.
template <int N, int KSPLIT>
__global__ __launch_bounds__(256) void reduce_relu(
    const float* __restrict__ P, const float* __restrict__ bias,
    __bf16* __restrict__ H, const int* __restrict__ off)
{
    int row = blockIdx.y;
    if (row >= off[EE]) return;
    int e = 0;
#pragma unroll
    for (int t = 0; t < EE - 1; ++t) if (row >= off[t + 1]) e = t + 1;
    int col = blockIdx.x * 1024 + threadIdx.x * 4;
    f32x4 s = *(const f32x4*)(P + (size_t)row * N + col);
#pragma unroll
    for (int k = 1; k < KSPLIT; ++k)
        s += *(const f32x4*)(P + (size_t)k * RMAX * N + (size_t)row * N + col);
    s += *(const f32x4*)(bias + (size_t)e * N + col);
    __bf16 o[4];
#pragma unroll
    for (int c = 0; c < 4; ++c) o[c] = (__bf16)fmaxf(s[c], 0.f);
    *(uint2*)(H + (size_t)row * N + col) = *(uint2*)o;
}

// ---------------- combine: out[b] = sum_k w_k * (sum_s P3[s][r_k] + b3[e_k]) ----------------
__global__ __launch_bounds__(256) void combine_kernel(
    const float* __restrict__ P3, const float* __restrict__ b3, const int* __restrict__ off,
    const int* __restrict__ tok_e, const int* __restrict__ tok_p,
    const float* __restrict__ tok_w, float* __restrict__ out)
{
    int b = blockIdx.x, t = threadIdx.x;
    int e0 = tok_e[2 * b], e1 = tok_e[2 * b + 1];
    int r0 = off[e0] + tok_p[2 * b];
    int r1 = off[e1] + tok_p[2 * b + 1];
    float w0 = tok_w[2 * b], w1 = tok_w[2 * b + 1];
    int col = t * 4;
    f32x4 s0 = *(const f32x4*)(P3 + (size_t)r0 * OO + col);
    f32x4 s1 = *(const f32x4*)(P3 + (size_t)r1 * OO + col);
#pragma unroll
    for (int k = 1; k < 4; ++k) {
        s0 += *(const f32x4*)(P3 + (size_t)k * RMAX * OO + (size_t)r0 * OO + col);
        s1 += *(const f32x4*)(P3 + (size_t)k * RMAX * OO + (size_t)r1 * OO + col);
    }
    s0 += *(const f32x4*)(b3 + (size_t)e0 * OO + col);
    s1 += *(const f32x4*)(b3 + (size_t)e1 * OO + col);
    f32x4 o = s0 * w0 + s1 * w1;
    *(f32x4*)(out + (size_t)b * OO + col) = o;
}

extern "C" void kernel_launch(void* const* d_in, const int* in_sizes, int n_in,
                              void* d_out, int out_size, void* d_ws, size_t ws_size,
                              hipStream_t stream)
{
    (void)in_sizes; (void)n_in; (void)out_size; (void)ws_size;
    const float* x  = (const float*)d_in[0];
    const float* Wr = (const float*)d_in[1];
    const float* br = (const float*)d_in[2];
    const float* W1 = (const float*)d_in[3];
    const float* b1 = (const float*)d_in[4];
    const float* W2 = (const float*)d_in[5];
    const float* b2 = (const float*)d_in[6];
    const float* W3 = (const float*)d_in[7];
    const float* b3 = (const float*)d_in[8];
    float* out = (float*)d_out;

    char* ws = (char*)d_ws;
    int*    counts = (int*)(ws + 0);
    int*    off    = (int*)(ws + 256);
    int*    tok_e  = (int*)(ws + 1024);
    int*    tok_p  = (int*)(ws + 9216);
    float*  tok_w  = (float*)(ws + 17408);
    int*    elist  = (int*)(ws + 25600);
    __bf16* Xg     = (__bf16*)(ws + 65536);
    __bf16* H1     = (__bf16*)(ws + 6356992);
    __bf16* H2     = (__bf16*)(ws + 18939904);
    float*  P1     = (float*)(ws + 31522816);
    float*  P2     = (float*)(ws + 81854464);
    float*  P3     = (float*)(ws + 132186112);

    hipMemsetAsync(counts, 0, 256, stream);
    router_kernel<<<1024, 256, 0, stream>>>(x, Wr, br, counts, elist, tok_e, tok_p, tok_w);
    offsets_kernel<<<1, 64, 0, stream>>>(counts, off);
    gather_kernel<<<dim3(32, 8), 256, 0, stream>>>(x, counts, off, elist, Xg);

    // split-K GEMMs: ~1024 active blocks each (~4/CU) to overlap the per-step latency chain
    gemm_splitk<1024, 2048, 2><<<dim3(32, 16, 8), 256, 0, stream>>>(Xg, W1, P1, counts, off);
    reduce_relu<2048, 2><<<dim3(2, RMAX), 256, 0, stream>>>(P1, b1, H1, off);
    gemm_splitk<2048, 2048, 2><<<dim3(32, 16, 8), 256, 0, stream>>>(H1, W2, P2, counts, off);
    reduce_relu<2048, 2><<<dim3(2, RMAX), 256, 0, stream>>>(P2, b2, H2, off);
    gemm_splitk<2048, 1024, 4><<<dim3(16, 32, 8), 256, 0, stream>>>(H2, W3, P3, counts, off);

    combine_kernel<<<1024, 256, 0, stream>>>(P3, b3, off, tok_e, tok_p, tok_w, out);
}